// Round 9
// baseline (3004.292 us; speedup 1.0000x reference)
//
#include <hip/hip_runtime.h>
#include <hip/hip_fp16.h>

static constexpr int KIN  = 25;
static constexpr int KOUT = 5;
static constexpr int BSH  = 10;          // dst bucket = 1024 nodes
static constexpr int NPB  = 1 << BSH;
static constexpr int SBSH = 11;          // src bucket = 2048 nodes
static constexpr int SPB  = 1 << SBSH;
static constexpr int DROW = 1024;        // dst table stride (NDB <= 1024)
static constexpr int SROW = 512;         // src table stride (NSB <= 512)
static constexpr int NBLK = 512;         // blocks for histd/scatter1
static constexpr int BTH  = 512;

// ---------------------------------------------------------------------------
// k_node1: xl5 = x@Wl (stride 5), xr5 = x@Wr (stride 5)
// ---------------------------------------------------------------------------
__global__ __launch_bounds__(256) void k_node1(
    const float* __restrict__ x,
    const float* __restrict__ Wl, const float* __restrict__ Wr,
    float* __restrict__ xl5, float* __restrict__ xr5, int n)
{
    __shared__ float sWl[KIN * KOUT];
    __shared__ float sWr[KIN * KOUT];
    __shared__ float sx[256 * KIN];

    const int tid = threadIdx.x;
    if (tid < KIN * KOUT) { sWl[tid] = Wl[tid]; sWr[tid] = Wr[tid]; }

    const int base = blockIdx.x * 256;
    const int cnt  = min(256, n - base);
    const size_t xbase = (size_t)base * KIN;
    for (int i = tid; i < cnt * KIN; i += 256) sx[i] = x[xbase + i];
    __syncthreads();

    if (tid >= cnt) return;
    const int node = base + tid;

    float xls[KOUT] = {0.f, 0.f, 0.f, 0.f, 0.f};
    float xrs[KOUT] = {0.f, 0.f, 0.f, 0.f, 0.f};
    const float* xp = &sx[tid * KIN];
#pragma unroll
    for (int i = 0; i < KIN; ++i) {
        const float xv = xp[i];
#pragma unroll
        for (int o = 0; o < KOUT; ++o) {
            xls[o] += xv * sWl[i * KOUT + o];
            xrs[o] += xv * sWr[i * KOUT + o];
        }
    }
    const size_t n5 = (size_t)node * 5;
#pragma unroll
    for (int o = 0; o < KOUT; ++o) { xl5[n5 + o] = xls[o]; xr5[n5 + o] = xrs[o]; }
}

// ---------------------------------------------------------------------------
// k_histd: per-block dst-bucket histogram.
// ---------------------------------------------------------------------------
__global__ __launch_bounds__(BTH) void k_histd(
    const int* __restrict__ dst, int E, int NDB, int* __restrict__ hist_blk)
{
    __shared__ int h[DROW];
    const int b = blockIdx.x, tid = threadIdx.x;
    for (int i = tid; i < DROW; i += BTH) h[i] = 0;
    __syncthreads();
    const int chunk = (E + NBLK - 1) / NBLK;
    const int eb = b * chunk, ee = min(E, eb + chunk);
    for (int i = eb + tid; i < ee; i += BTH)
        atomicAdd(&h[dst[i] >> BSH], 1);
    __syncthreads();
    for (int i = tid; i < DROW; i += BTH) hist_blk[b * DROW + i] = h[i];
}

// ---------------------------------------------------------------------------
// k_sumoffs_d: hist_blk -> per-block exclusive offsets (in place) + totals.
// ---------------------------------------------------------------------------
__global__ __launch_bounds__(256) void k_sumoffs_d(
    int* __restrict__ hist_blk, int NDB, int* __restrict__ totals)
{
    const int i = blockIdx.x * 256 + threadIdx.x;
    if (i >= NDB) return;
    int s = 0;
    for (int b = 0; b < NBLK; ++b) {
        const int t = hist_blk[b * DROW + i];
        hist_blk[b * DROW + i] = s;
        s += t;
    }
    totals[i] = s;
}

// ---------------------------------------------------------------------------
// k_scan: one block of 1024, exclusive scan of totals[0..len) -> base[0..len].
// ---------------------------------------------------------------------------
__global__ __launch_bounds__(1024) void k_scan(
    const int* __restrict__ totals, int* __restrict__ base, int len)
{
    __shared__ int s[1024];
    const int t = threadIdx.x;
    const int v = (t < len) ? totals[t] : 0;
    s[t] = v;
    __syncthreads();
    for (int off = 1; off < 1024; off <<= 1) {
        const int u = (t >= off) ? s[t - off] : 0;
        __syncthreads();
        s[t] += u;
        __syncthreads();
    }
    if (t < len) base[t] = s[t] - v;
    if (t == 1023) base[len] = s[1023];
}

// ---------------------------------------------------------------------------
// k_scatter1: dst-bin edges. rs1[pos] = (src << BSH) | dst_local.
// ---------------------------------------------------------------------------
__global__ __launch_bounds__(BTH) void k_scatter1(
    const int* __restrict__ src, const int* __restrict__ dst, int E, int NDB,
    const int* __restrict__ hist_blk, const int* __restrict__ base_d,
    int* __restrict__ rs1)
{
    __shared__ int cur[DROW];
    const int b = blockIdx.x, tid = threadIdx.x;
    for (int i = tid; i < NDB; i += BTH)
        cur[i] = base_d[i] + hist_blk[b * DROW + i];
    __syncthreads();
    const int chunk = (E + NBLK - 1) / NBLK;
    const int eb = b * chunk, ee = min(E, eb + chunk);
    for (int i = eb + tid; i < ee; i += BTH) {
        const int d = dst[i];
        const int pos = atomicAdd(&cur[d >> BSH], 1);
        rs1[pos] = (src[i] << BSH) | (d & (NPB - 1));
    }
}

// ---------------------------------------------------------------------------
// k_histseg: per dst-bucket, count edges per src-bucket -> hist_seg[d][s].
// ---------------------------------------------------------------------------
__global__ __launch_bounds__(512) void k_histseg(
    const int* __restrict__ rs1, const int* __restrict__ base_d,
    int* __restrict__ hist_seg)
{
    __shared__ int h[SROW];
    const int d = blockIdx.x, tid = threadIdx.x;
    h[tid] = 0;
    __syncthreads();
    const int eb = base_d[d], ee = base_d[d + 1];
    for (int i = eb + tid; i < ee; i += 512)
        atomicAdd(&h[rs1[i] >> (BSH + SBSH)], 1);
    __syncthreads();
    hist_seg[d * SROW + tid] = h[tid];
}

// ---------------------------------------------------------------------------
// k_sumoffs_s: per src-bucket column, exclusive cumsum over d in place;
// row NDB = totals; totals_s copy.
// ---------------------------------------------------------------------------
__global__ __launch_bounds__(256) void k_sumoffs_s(
    int* __restrict__ hist_seg, int NDB, int* __restrict__ totals_s)
{
    const int i = blockIdx.x * 256 + threadIdx.x;
    if (i >= SROW) return;
    int run = 0;
    for (int d = 0; d < NDB; ++d) {
        const int t = hist_seg[d * SROW + i];
        hist_seg[d * SROW + i] = run;
        run += t;
    }
    hist_seg[NDB * SROW + i] = run;
    totals_s[i] = run;
}

// ---------------------------------------------------------------------------
// k_scatter_s: per dst-bucket, assign each edge (a) its src-binned slot p2
// (for rs2) and (b) its final dst-sorted slot posd (s-sorted within segment).
// ---------------------------------------------------------------------------
__global__ __launch_bounds__(512) void k_scatter_s(
    const int* __restrict__ rs1, const int* __restrict__ base_d,
    const int* __restrict__ base_s, const int* __restrict__ hist_seg,
    int NDB,
    unsigned short* __restrict__ rs2sl, int* __restrict__ rs2pos,
    unsigned short* __restrict__ rsdl)
{
    __shared__ int sc[SROW];
    __shared__ int curG[SROW];
    __shared__ int curL[SROW];
    const int d = blockIdx.x, t = threadIdx.x;

    const int so0 = hist_seg[d * SROW + t];
    const int so1 = hist_seg[(d + 1) * SROW + t];
    const int raw = so1 - so0;
    sc[t] = raw;
    __syncthreads();
    for (int off = 1; off < SROW; off <<= 1) {
        const int u = (t >= off) ? sc[t - off] : 0;
        __syncthreads();
        sc[t] += u;
        __syncthreads();
    }
    curL[t] = base_d[d] + sc[t] - raw;      // exclusive within-segment offset
    curG[t] = base_s[t] + so0;              // global s-binned position
    __syncthreads();

    const int eb = base_d[d], ee = base_d[d + 1];
    for (int i = eb + t; i < ee; i += 512) {
        const int v = rs1[i];
        const int s  = v >> (BSH + SBSH);
        const int sl = (v >> BSH) & (SPB - 1);
        const int dl = v & (NPB - 1);
        const int p2   = atomicAdd(&curG[s], 1);
        const int posd = atomicAdd(&curL[s], 1);
        rs2sl[p2]  = (unsigned short)sl;
        rs2pos[p2] = posd;
        rsdl[posd] = (unsigned short)dl;
    }
}

// ---------------------------------------------------------------------------
// k_expand: per src-bucket, stage xl window in LDS, write payload to each
// edge's dst-sorted slot. HP=1: fp16 payload.
// ---------------------------------------------------------------------------
template <int HP>
__global__ __launch_bounds__(256) void k_expand(
    const float* __restrict__ xl5,
    const unsigned short* __restrict__ rs2sl, const int* __restrict__ rs2pos,
    const int* __restrict__ base_s,
    void* __restrict__ pay4v, void* __restrict__ payEv, int n)
{
    __shared__ float w5[SPB * 5];           // 40 KB
    const int sb = blockIdx.x, tid = threadIdx.x;
    const int node0 = sb << SBSH;
    const int nns = min(SPB, n - node0);
    for (int i = tid; i < nns * 5; i += 256) w5[i] = xl5[(size_t)node0 * 5 + i];
    __syncthreads();

    const int eb = base_s[sb], ee = base_s[sb + 1];
    for (int i = eb + tid; i < ee; i += 256) {
        const int sl = rs2sl[i];
        const int p  = rs2pos[i];
        const float* w = &w5[sl * 5];
        if (HP) {
            ushort4 u;
            u.x = __half_as_ushort(__float2half(w[0]));
            u.y = __half_as_ushort(__float2half(w[1]));
            u.z = __half_as_ushort(__float2half(w[2]));
            u.w = __half_as_ushort(__float2half(w[3]));
            ((ushort4*)pay4v)[p] = u;
            ((unsigned short*)payEv)[p] = __half_as_ushort(__float2half(w[4]));
        } else {
            float4 f; f.x = w[0]; f.y = w[1]; f.z = w[2]; f.w = w[3];
            ((float4*)pay4v)[p] = f;
            ((float*)payEv)[p] = w[4];
        }
    }
}

// ---------------------------------------------------------------------------
// k_gather2: per dst-bucket. Sequential payload stream + LDS xr window +
// LDS acc. Epilogue folds self-loop + bias + LeakyReLU(0.1).
// ---------------------------------------------------------------------------
template <int HP>
__global__ __launch_bounds__(256) void k_gather2(
    const void* __restrict__ pay4v, const void* __restrict__ payEv,
    const unsigned short* __restrict__ rsdl, const int* __restrict__ base_d,
    const float* __restrict__ xl5, const float* __restrict__ xr5,
    const float* __restrict__ att, const float* __restrict__ bias,
    float* __restrict__ xout, int n)
{
    __shared__ float acc[NPB][6];           // 24 KB
    __shared__ float xrw[NPB * 5];          // 20 KB
    const int d = blockIdx.x, tid = threadIdx.x;
    const int node0 = d << BSH;
    const int nn = min(NPB, n - node0);

    for (int i = tid; i < NPB * 6; i += 256) ((float*)acc)[i] = 0.f;
    for (int i = tid; i < nn * 5; i += 256) xrw[i] = xr5[(size_t)node0 * 5 + i];
    __syncthreads();

    const float a0 = att[0], a1 = att[1], a2 = att[2], a3 = att[3], a4 = att[4];
    const int eb = base_d[d], ee = base_d[d + 1];

#define G2_BODY(X0, X1, X2, X3, X4, DL)                                       \
    {                                                                         \
        const float* xr = &xrw[(DL) * 5];                                     \
        float t, lg = 0.f;                                                    \
        t = X0 + xr[0]; t = (t >= 0.f) ? t : 0.2f * t; lg += t * a0;          \
        t = X1 + xr[1]; t = (t >= 0.f) ? t : 0.2f * t; lg += t * a1;          \
        t = X2 + xr[2]; t = (t >= 0.f) ? t : 0.2f * t; lg += t * a2;          \
        t = X3 + xr[3]; t = (t >= 0.f) ? t : 0.2f * t; lg += t * a3;          \
        t = X4 + xr[4]; t = (t >= 0.f) ? t : 0.2f * t; lg += t * a4;          \
        const float w = __expf(lg);                                           \
        atomicAdd(&acc[DL][0], w * X0);                                       \
        atomicAdd(&acc[DL][1], w * X1);                                       \
        atomicAdd(&acc[DL][2], w * X2);                                       \
        atomicAdd(&acc[DL][3], w * X3);                                       \
        atomicAdd(&acc[DL][4], w * X4);                                       \
        atomicAdd(&acc[DL][5], w);                                            \
    }

    int i = eb + tid;
    for (; i + 256 < ee; i += 512) {
        const int dl0 = rsdl[i], dl1 = rsdl[i + 256];
        float x00, x01, x02, x03, x04, x10, x11, x12, x13, x14;
        if (HP) {
            const ushort4 u0 = ((const ushort4*)pay4v)[i];
            const ushort4 u1 = ((const ushort4*)pay4v)[i + 256];
            const unsigned short e0 = ((const unsigned short*)payEv)[i];
            const unsigned short e1 = ((const unsigned short*)payEv)[i + 256];
            x00 = __half2float(__ushort_as_half(u0.x));
            x01 = __half2float(__ushort_as_half(u0.y));
            x02 = __half2float(__ushort_as_half(u0.z));
            x03 = __half2float(__ushort_as_half(u0.w));
            x04 = __half2float(__ushort_as_half(e0));
            x10 = __half2float(__ushort_as_half(u1.x));
            x11 = __half2float(__ushort_as_half(u1.y));
            x12 = __half2float(__ushort_as_half(u1.z));
            x13 = __half2float(__ushort_as_half(u1.w));
            x14 = __half2float(__ushort_as_half(e1));
        } else {
            const float4 f0 = ((const float4*)pay4v)[i];
            const float4 f1 = ((const float4*)pay4v)[i + 256];
            x00 = f0.x; x01 = f0.y; x02 = f0.z; x03 = f0.w;
            x04 = ((const float*)payEv)[i];
            x10 = f1.x; x11 = f1.y; x12 = f1.z; x13 = f1.w;
            x14 = ((const float*)payEv)[i + 256];
        }
        G2_BODY(x00, x01, x02, x03, x04, dl0)
        G2_BODY(x10, x11, x12, x13, x14, dl1)
    }
    if (i < ee) {
        const int dl = rsdl[i];
        float x0, x1, x2, x3, x4;
        if (HP) {
            const ushort4 u = ((const ushort4*)pay4v)[i];
            x0 = __half2float(__ushort_as_half(u.x));
            x1 = __half2float(__ushort_as_half(u.y));
            x2 = __half2float(__ushort_as_half(u.z));
            x3 = __half2float(__ushort_as_half(u.w));
            x4 = __half2float(__ushort_as_half(((const unsigned short*)payEv)[i]));
        } else {
            const float4 f = ((const float4*)pay4v)[i];
            x0 = f.x; x1 = f.y; x2 = f.z; x3 = f.w;
            x4 = ((const float*)payEv)[i];
        }
        G2_BODY(x0, x1, x2, x3, x4, dl)
    }
    __syncthreads();

    const float b0 = bias[0], b1 = bias[1], b2 = bias[2], b3 = bias[3], b4 = bias[4];
    for (int l = tid; l < nn; l += 256) {
        const int node = node0 + l;
        const size_t n5 = (size_t)node * 5;
        const float y0 = xl5[n5 + 0], y1 = xl5[n5 + 1], y2 = xl5[n5 + 2],
                    y3 = xl5[n5 + 3], y4 = xl5[n5 + 4];
        const float* xr = &xrw[l * 5];
        float t, lg = 0.f;
        t = y0 + xr[0]; t = (t >= 0.f) ? t : 0.2f * t; lg += t * a0;
        t = y1 + xr[1]; t = (t >= 0.f) ? t : 0.2f * t; lg += t * a1;
        t = y2 + xr[2]; t = (t >= 0.f) ? t : 0.2f * t; lg += t * a2;
        t = y3 + xr[3]; t = (t >= 0.f) ? t : 0.2f * t; lg += t * a3;
        t = y4 + xr[4]; t = (t >= 0.f) ? t : 0.2f * t; lg += t * a4;
        const float w = __expf(lg);

        const float inv = 1.0f / (acc[l][5] + w);
        float v;
        v = (acc[l][0] + w * y0) * inv + b0; xout[n5 + 0] = (v >= 0.f) ? v : 0.1f * v;
        v = (acc[l][1] + w * y1) * inv + b1; xout[n5 + 1] = (v >= 0.f) ? v : 0.1f * v;
        v = (acc[l][2] + w * y2) * inv + b2; xout[n5 + 2] = (v >= 0.f) ? v : 0.1f * v;
        v = (acc[l][3] + w * y3) * inv + b3; xout[n5 + 3] = (v >= 0.f) ? v : 0.1f * v;
        v = (acc[l][4] + w * y4) * inv + b4; xout[n5 + 4] = (v >= 0.f) ? v : 0.1f * v;
    }
#undef G2_BODY
}

// ---------------------------------------------------------------------------
// k_mlp: fused projection + classifier.
// ---------------------------------------------------------------------------
__global__ __launch_bounds__(256) void k_mlp(
    const float* __restrict__ xp, const float* __restrict__ xs,
    const float* __restrict__ xv,
    const float* __restrict__ Wp1, const float* __restrict__ bp1,
    const float* __restrict__ Wp2, const float* __restrict__ bp2,
    const float* __restrict__ Wc1, const float* __restrict__ bc1,
    const float* __restrict__ Wc2, const float* __restrict__ bc2,
    float* __restrict__ out, int n)
{
    __shared__ float sW[257];
    const int tid = threadIdx.x;
    if (tid < 150) sW[tid] = Wp1[tid];
    if (tid < 10)  sW[150 + tid] = bp1[tid];
    if (tid < 50)  sW[160 + tid] = Wp2[tid];
    if (tid < 5)   sW[210 + tid] = bp2[tid];
    if (tid < 25)  sW[215 + tid] = Wc1[tid];
    if (tid < 5)   sW[240 + tid] = bc1[tid];
    if (tid < 10)  sW[245 + tid] = Wc2[tid];
    if (tid < 2)   sW[255 + tid] = bc2[tid];
    __syncthreads();

    const int node = blockIdx.x * 256 + tid;
    if (node >= n) return;
    const size_t n5 = (size_t)node * KOUT;

    float h[15];
#pragma unroll
    for (int k = 0; k < 5; ++k) {
        h[k]      = xp[n5 + k];
        h[5 + k]  = xs[n5 + k];
        h[10 + k] = xv[n5 + k];
    }

    float t1[10];
#pragma unroll
    for (int o = 0; o < 10; ++o) {
        float a = sW[150 + o];
#pragma unroll
        for (int i = 0; i < 15; ++i) a += h[i] * sW[i * 10 + o];
        t1[o] = (a >= 0.f) ? a : 0.1f * a;
    }

    float t2[5];
#pragma unroll
    for (int o = 0; o < 5; ++o) {
        float a = sW[210 + o];
#pragma unroll
        for (int i = 0; i < 10; ++i) a += t1[i] * sW[160 + i * 5 + o];
        t2[o] = a;
    }

    float t3[5];
#pragma unroll
    for (int o = 0; o < 5; ++o) {
        float a = sW[240 + o];
#pragma unroll
        for (int i = 0; i < 5; ++i) a += t2[i] * sW[215 + i * 5 + o];
        t3[o] = (a >= 0.f) ? a : 0.1f * a;
    }

    float o0 = sW[255], o1 = sW[256];
#pragma unroll
    for (int i = 0; i < 5; ++i) {
        o0 += t3[i] * sW[245 + i * 2 + 0];
        o1 += t3[i] * sW[245 + i * 2 + 1];
    }
    out[(size_t)node * 2 + 0] = o0;
    out[(size_t)node * 2 + 1] = o1;
}

// ---------------------------------------------------------------------------
extern "C" void kernel_launch(void* const* d_in, const int* in_sizes, int n_in,
                              void* d_out, int out_size, void* d_ws, size_t ws_size,
                              hipStream_t stream)
{
    const float* x = (const float*)d_in[0];
    const int n = in_sizes[0] / KIN;              // 1,000,000
    const int E = in_sizes[1] / 2;                // 8,000,000
    const int NDB = (n + NPB - 1) >> BSH;         // 977
    const int NSB = (n + SPB - 1) >> SBSH;        // 489

    const int* ei[3] = { (const int*)d_in[1], (const int*)d_in[2], (const int*)d_in[3] };
    const float *Wl[3], *Wr[3], *att[3], *bias[3];
    for (int r = 0; r < 3; ++r) {
        const int base = 4 + r * 4;
        Wl[r]   = (const float*)d_in[base + 0];
        Wr[r]   = (const float*)d_in[base + 1];
        att[r]  = (const float*)d_in[base + 2];
        bias[r] = (const float*)d_in[base + 3];
    }
    const float* Wp1 = (const float*)d_in[16];
    const float* bp1 = (const float*)d_in[17];
    const float* Wp2 = (const float*)d_in[18];
    const float* bp2 = (const float*)d_in[19];
    const float* Wc1 = (const float*)d_in[20];
    const float* bc1 = (const float*)d_in[21];
    const float* Wc2 = (const float*)d_in[22];
    const float* bc2 = (const float*)d_in[23];

    // ---- workspace layout (per-relation buffer reuse) ----
    const size_t tail_bytes =
        (size_t)E * 4 /*rs1*/ + (size_t)E * 4 /*rs2pos*/ +
        (size_t)E * 2 /*rs2sl*/ + (size_t)E * 2 /*rsdl*/ +
        (size_t)NBLK * DROW * 4 + (size_t)(DROW + 1) * SROW * 4 +
        (size_t)DROW * 4 + (size_t)(DROW + 1) * 4 +
        (size_t)SROW * 4 + (size_t)(SROW + 1) * 4 + 256;
    const size_t fbytes = (size_t)25 * n * 4;     // xout(15n)+xl5(5n)+xr5(5n)
    const size_t need_fp = fbytes + (size_t)E * 20 + tail_bytes;
    const bool hp = ws_size < need_fp;            // fp16 payload if tight

    char* p = (char*)d_ws;
    float* xout = (float*)p;  p += (size_t)15 * n * 4;
    float* xl5  = (float*)p;  p += (size_t)5 * n * 4;
    float* xr5  = (float*)p;  p += (size_t)5 * n * 4;
    void*  pay4 = (void*)p;   p += (size_t)E * (hp ? 8 : 16);
    void*  payE = (void*)p;   p += (size_t)E * (hp ? 2 : 4);
    int*   rs1    = (int*)p;  p += (size_t)E * 4;
    int*   rs2pos = (int*)p;  p += (size_t)E * 4;
    unsigned short* rs2sl = (unsigned short*)p; p += (size_t)E * 2;
    unsigned short* rsdl  = (unsigned short*)p; p += (size_t)E * 2;
    int* hist_blk = (int*)p;  p += (size_t)NBLK * DROW * 4;
    int* hist_seg = (int*)p;  p += (size_t)(DROW + 1) * SROW * 4;
    int* totals_d = (int*)p;  p += (size_t)DROW * 4;
    int* base_d   = (int*)p;  p += (size_t)(DROW + 1) * 4;
    int* totals_s = (int*)p;  p += (size_t)SROW * 4;
    int* base_s   = (int*)p;

    const int nb_node = (n + 255) / 256;

    for (int r = 0; r < 3; ++r) {
        const int* src = ei[r];
        const int* dst = ei[r] + E;
        float* xo = xout + (size_t)r * 5 * n;

        k_node1   <<<nb_node, 256, 0, stream>>>(x, Wl[r], Wr[r], xl5, xr5, n);
        k_histd   <<<NBLK, BTH, 0, stream>>>(dst, E, NDB, hist_blk);
        k_sumoffs_d<<<(NDB + 255) / 256, 256, 0, stream>>>(hist_blk, NDB, totals_d);
        k_scan    <<<1, 1024, 0, stream>>>(totals_d, base_d, NDB);
        k_scatter1<<<NBLK, BTH, 0, stream>>>(src, dst, E, NDB, hist_blk, base_d, rs1);
        k_histseg <<<NDB, 512, 0, stream>>>(rs1, base_d, hist_seg);
        k_sumoffs_s<<<(SROW + 255) / 256, 256, 0, stream>>>(hist_seg, NDB, totals_s);
        k_scan    <<<1, 1024, 0, stream>>>(totals_s, base_s, NSB);
        k_scatter_s<<<NDB, 512, 0, stream>>>(rs1, base_d, base_s, hist_seg, NDB,
                                             rs2sl, rs2pos, rsdl);
        if (hp) {
            k_expand<1> <<<NSB, 256, 0, stream>>>(xl5, rs2sl, rs2pos, base_s,
                                                  pay4, payE, n);
            k_gather2<1><<<NDB, 256, 0, stream>>>(pay4, payE, rsdl, base_d,
                                                  xl5, xr5, att[r], bias[r], xo, n);
        } else {
            k_expand<0> <<<NSB, 256, 0, stream>>>(xl5, rs2sl, rs2pos, base_s,
                                                  pay4, payE, n);
            k_gather2<0><<<NDB, 256, 0, stream>>>(pay4, payE, rsdl, base_d,
                                                  xl5, xr5, att[r], bias[r], xo, n);
        }
    }

    k_mlp<<<nb_node, 256, 0, stream>>>(xout, xout + (size_t)5 * n, xout + (size_t)10 * n,
                                       Wp1, bp1, Wp2, bp2, Wc1, bc1, Wc2, bc2,
                                       (float*)d_out, n);
}

// Round 10
// 1116.407 us; speedup vs baseline: 2.6910x; 2.6910x over previous
//
#include <hip/hip_runtime.h>

static constexpr int KIN  = 25;
static constexpr int KOUT = 5;
static constexpr int NBLK = 512;      // blocks for hist/scatter
static constexpr int BTH  = 1024;     // threads for hist/scatter
static constexpr int BSH  = 9;        // log2 nodes per bucket
static constexpr int NPB  = 1 << BSH; // 512 nodes per bucket
static constexpr int NBH  = 2048;     // hist row stride / max buckets
static constexpr int BROW = NBH + 1;  // base row stride (incl. sentinel)
static constexpr int CAP  = 5120;     // max edges per bucket for LDS sort (16 sigma)

// ---------------------------------------------------------------------------
// k_node1: single-relation transforms (fallback layout).
// ---------------------------------------------------------------------------
__global__ __launch_bounds__(256) void k_node1(
    const float* __restrict__ x,
    const float* __restrict__ Wl, const float* __restrict__ Wr,
    float* __restrict__ xl8, float* __restrict__ xr5, int n)
{
    __shared__ float sWl[KIN * KOUT];
    __shared__ float sWr[KIN * KOUT];
    __shared__ float sx[256 * KIN];

    const int tid = threadIdx.x;
    if (tid < KIN * KOUT) { sWl[tid] = Wl[tid]; sWr[tid] = Wr[tid]; }

    const int base = blockIdx.x * 256;
    const int cnt  = min(256, n - base);
    const size_t xbase = (size_t)base * KIN;
    for (int i = tid; i < cnt * KIN; i += 256) sx[i] = x[xbase + i];
    __syncthreads();

    if (tid >= cnt) return;
    const int node = base + tid;

    float xls[KOUT] = {0.f, 0.f, 0.f, 0.f, 0.f};
    float xrs[KOUT] = {0.f, 0.f, 0.f, 0.f, 0.f};
    const float* xp = &sx[tid * KIN];
#pragma unroll
    for (int i = 0; i < KIN; ++i) {
        const float xv = xp[i];
#pragma unroll
        for (int o = 0; o < KOUT; ++o) {
            xls[o] += xv * sWl[i * KOUT + o];
            xrs[o] += xv * sWr[i * KOUT + o];
        }
    }

    const size_t n8 = (size_t)node * 8;
    float4 v4;
    v4.x = xls[0]; v4.y = xls[1]; v4.z = xls[2]; v4.w = xls[3];
    *(float4*)(xl8 + n8) = v4;
    xl8[n8 + 4] = xls[4];
    const size_t n5 = (size_t)node * 5;
#pragma unroll
    for (int o = 0; o < KOUT; ++o) xr5[n5 + o] = xrs[o];
}

// ---------------------------------------------------------------------------
// k_node3: all three relations in one pass over x.
// ---------------------------------------------------------------------------
__global__ __launch_bounds__(256) void k_node3(
    const float* __restrict__ x,
    const float* __restrict__ Wl0, const float* __restrict__ Wr0,
    const float* __restrict__ Wl1, const float* __restrict__ Wr1,
    const float* __restrict__ Wl2, const float* __restrict__ Wr2,
    float* __restrict__ xl8, float* __restrict__ xr5,  // [3][n][*]
    int n)
{
    __shared__ float sWl[3][KIN * KOUT];
    __shared__ float sWr[3][KIN * KOUT];
    __shared__ float sx[256 * KIN];

    const int tid = threadIdx.x;
    if (tid < KIN * KOUT) {
        sWl[0][tid] = Wl0[tid]; sWr[0][tid] = Wr0[tid];
        sWl[1][tid] = Wl1[tid]; sWr[1][tid] = Wr1[tid];
        sWl[2][tid] = Wl2[tid]; sWr[2][tid] = Wr2[tid];
    }

    const int base = blockIdx.x * 256;
    const int cnt  = min(256, n - base);
    const size_t xbase = (size_t)base * KIN;
    for (int i = tid; i < cnt * KIN; i += 256) sx[i] = x[xbase + i];
    __syncthreads();

    if (tid >= cnt) return;
    const int node = base + tid;

    float xls[3][KOUT] = {};
    float xrs[3][KOUT] = {};
    const float* xp = &sx[tid * KIN];
#pragma unroll
    for (int i = 0; i < KIN; ++i) {
        const float xv = xp[i];
#pragma unroll
        for (int r = 0; r < 3; ++r)
#pragma unroll
            for (int o = 0; o < KOUT; ++o) {
                xls[r][o] += xv * sWl[r][i * KOUT + o];
                xrs[r][o] += xv * sWr[r][i * KOUT + o];
            }
    }

#pragma unroll
    for (int r = 0; r < 3; ++r) {
        const size_t n8 = (size_t)r * n * 8 + (size_t)node * 8;
        float4 v4;
        v4.x = xls[r][0]; v4.y = xls[r][1]; v4.z = xls[r][2]; v4.w = xls[r][3];
        *(float4*)(xl8 + n8) = v4;
        xl8[n8 + 4] = xls[r][4];
        const size_t n5 = (size_t)r * n * 5 + (size_t)node * 5;
#pragma unroll
        for (int o = 0; o < KOUT; ++o) xr5[n5 + o] = xrs[r][o];
    }
}

// ---------------------------------------------------------------------------
// k_hist3: per-block bucket histogram of dst. blockIdx.y = relation.
// ---------------------------------------------------------------------------
__global__ __launch_bounds__(BTH) void k_hist3(
    const int* __restrict__ d0p, const int* __restrict__ d1p,
    const int* __restrict__ d2p, int E, int NB, int* __restrict__ hist3)
{
    __shared__ int h[NBH];
    const int rel = blockIdx.y, b = blockIdx.x, tid = threadIdx.x;
    const int* dst = (rel == 0) ? d0p : (rel == 1 ? d1p : d2p);
    int* hist_blk = hist3 + (size_t)rel * NBLK * NBH;

    for (int i = tid; i < NB; i += BTH) h[i] = 0;
    __syncthreads();
    const int chunk = (E + NBLK - 1) / NBLK;
    const int eb = b * chunk, ee = min(E, eb + chunk);
    for (int i = eb + tid; i < ee; i += BTH)
        atomicAdd(&h[dst[i] >> BSH], 1);
    __syncthreads();
    for (int i = tid; i < NB; i += BTH) hist_blk[b * NBH + i] = h[i];
}

// ---------------------------------------------------------------------------
// k_sumoffs3: per bucket, hist rows -> exclusive per-block offsets + totals.
// ---------------------------------------------------------------------------
__global__ __launch_bounds__(256) void k_sumoffs3(
    int* __restrict__ hist3, int NB, int* __restrict__ totals3)
{
    const int rel = blockIdx.y;
    int* hist_blk = hist3 + (size_t)rel * NBLK * NBH;
    int* totals   = totals3 + rel * NBH;
    const int i = blockIdx.x * 256 + threadIdx.x;
    if (i >= NB) return;
    int s = 0;
    for (int b = 0; b < NBLK; ++b) {
        const int t = hist_blk[b * NBH + i];
        hist_blk[b * NBH + i] = s;
        s += t;
    }
    totals[i] = s;
}

// ---------------------------------------------------------------------------
// k_scan3: exclusive scan of totals -> base per relation. blockIdx.x = rel.
// ---------------------------------------------------------------------------
__global__ __launch_bounds__(1024) void k_scan3(
    const int* __restrict__ totals3, int E, int NB, int* __restrict__ base3)
{
    __shared__ int s[1024];
    const int rel = blockIdx.x;
    const int* totals = totals3 + rel * NBH;
    int* base = base3 + rel * BROW;

    const int t = threadIdx.x;
    const int i0 = 2 * t, i1 = 2 * t + 1;
    const int t0 = (i0 < NB) ? totals[i0] : 0;
    const int t1 = (i1 < NB) ? totals[i1] : 0;
    const int pair = t0 + t1;
    s[t] = pair;
    __syncthreads();
    for (int off = 1; off < 1024; off <<= 1) {
        int v = (t >= off) ? s[t - off] : 0;
        __syncthreads();
        s[t] += v;
        __syncthreads();
    }
    const int excl = s[t] - pair;
    base[i0] = excl;
    base[i1] = excl + t0;
    if (t == 1023) base[NBH] = E;
}

// ---------------------------------------------------------------------------
// k_scatter3: single pass, no global atomics. blockIdx.y = relation.
// ---------------------------------------------------------------------------
__global__ __launch_bounds__(BTH) void k_scatter3(
    const int* __restrict__ s0p, const int* __restrict__ s1p,
    const int* __restrict__ s2p,
    const int* __restrict__ d0p, const int* __restrict__ d1p,
    const int* __restrict__ d2p,
    int E, int NB,
    const int* __restrict__ hist3, const int* __restrict__ base3,
    int* __restrict__ rs3)
{
    __shared__ int cur[NBH];
    const int rel = blockIdx.y, b = blockIdx.x, tid = threadIdx.x;
    const int* src = (rel == 0) ? s0p : (rel == 1 ? s1p : s2p);
    const int* dst = (rel == 0) ? d0p : (rel == 1 ? d1p : d2p);
    const int* hist_blk = hist3 + (size_t)rel * NBLK * NBH;
    const int* base = base3 + rel * BROW;
    int* rs = rs3 + (size_t)rel * E;

    for (int i = tid; i < NB; i += BTH)
        cur[i] = base[i] + hist_blk[b * NBH + i];
    __syncthreads();
    const int chunk = (E + NBLK - 1) / NBLK;
    const int eb = b * chunk, ee = min(E, eb + chunk);
    for (int i = eb + tid; i < ee; i += BTH) {
        const int d = dst[i];
        const int bkt = d >> BSH;
        const int pos = atomicAdd(&cur[bkt], 1);          // LDS atomic
        rs[pos] = (src[i] << BSH) | (d & (NPB - 1));
    }
}

// ---------------------------------------------------------------------------
// k_gather4: one block per (relation, bucket). In-LDS counting sort by
// dst-local, then chunked register accumulation (6 LDS atomics only per
// run boundary instead of per edge). Epilogue folds self-loop+bias+lrelu.
// ---------------------------------------------------------------------------
template <int NREL>
__global__ __launch_bounds__(256) void k_gather4(
    const int* __restrict__ rs3, const int* __restrict__ base3,
    const float* __restrict__ xl8a, const float* __restrict__ xr5a,
    const float* __restrict__ at0, const float* __restrict__ at1,
    const float* __restrict__ at2,
    const float* __restrict__ bi0, const float* __restrict__ bi1,
    const float* __restrict__ bi2,
    float* __restrict__ xouta, int n, int E)
{
    __shared__ float acc[NPB][6];       // 12 KB
    __shared__ float xrw[NPB * 5];      // 10 KB
    __shared__ int   cur[NPB];          // 2 KB
    __shared__ int   sorted[CAP];       // 20 KB
    __shared__ int   sc[256];           // 1 KB

    const int bx  = blockIdx.x;
    const int rel = (NREL == 1) ? 0 : bx % NREL;
    const int bkt = (NREL == 1) ? bx : bx / NREL;

    const int*   rs   = rs3 + (size_t)rel * E;
    const int*   base = base3 + rel * BROW;
    const float* xl8  = xl8a + (size_t)rel * 8 * n;
    const float* xr5  = xr5a + (size_t)rel * 5 * n;
    const float* att  = (rel == 0) ? at0 : (rel == 1 ? at1 : at2);
    const float* bias = (rel == 0) ? bi0 : (rel == 1 ? bi1 : bi2);
    float*       xout = xouta + (size_t)rel * 5 * n;

    const int tid = threadIdx.x;
    const int node0 = bkt << BSH;
    const int nn = min(NPB, n - node0);

    for (int i = tid; i < NPB * 6; i += 256) ((float*)acc)[i] = 0.f;
    for (int i = tid; i < nn * 5; i += 256) xrw[i] = xr5[(size_t)node0 * 5 + i];
    for (int i = tid; i < NPB; i += 256) cur[i] = 0;
    __syncthreads();

    const float a0 = att[0], a1 = att[1], a2 = att[2], a3 = att[3], a4 = att[4];
    const int eb = base[bkt], ee = base[bkt + 1];
    const int seg = ee - eb;

    if (seg > 0 && seg <= CAP) {
        // --- histogram over dst-local ---
        for (int i = eb + tid; i < ee; i += 256)
            atomicAdd(&cur[rs[i] & (NPB - 1)], 1);
        __syncthreads();
        // --- block scan of 512 bins (2 per thread) ---
        const int h0 = cur[2 * tid], h1 = cur[2 * tid + 1];
        const int pair = h0 + h1;
        sc[tid] = pair;
        __syncthreads();
        for (int off = 1; off < 256; off <<= 1) {
            const int v = (tid >= off) ? sc[tid - off] : 0;
            __syncthreads();
            sc[tid] += v;
            __syncthreads();
        }
        const int excl = sc[tid] - pair;
        cur[2 * tid] = excl;
        cur[2 * tid + 1] = excl + h0;
        __syncthreads();
        // --- scatter into dl-sorted LDS order ---
        for (int i = eb + tid; i < ee; i += 256) {
            const int v = rs[i];
            const int p = atomicAdd(&cur[v & (NPB - 1)], 1);
            sorted[p] = v;
        }
        __syncthreads();
        // --- chunked register accumulation over sorted runs ---
        const int C  = (seg + 255) / 256;
        const int s0 = tid * C;
        const int s1 = min(seg, s0 + C);
        int curdl = -1;
        float A0 = 0.f, A1 = 0.f, A2 = 0.f, A3 = 0.f, A4 = 0.f, A5 = 0.f;
        float xr0 = 0.f, xr1 = 0.f, xr2 = 0.f, xr3 = 0.f, xr4 = 0.f;
        for (int i = s0; i < s1; ++i) {
            const int v  = sorted[i];
            const int dl = v & (NPB - 1);
            const int s  = v >> BSH;
            const size_t s8 = (size_t)s * 8;
            const float4 xs = *(const float4*)(xl8 + s8);
            const float  xs4 = xl8[s8 + 4];
            if (dl != curdl) {
                if (curdl >= 0) {
                    atomicAdd(&acc[curdl][0], A0);
                    atomicAdd(&acc[curdl][1], A1);
                    atomicAdd(&acc[curdl][2], A2);
                    atomicAdd(&acc[curdl][3], A3);
                    atomicAdd(&acc[curdl][4], A4);
                    atomicAdd(&acc[curdl][5], A5);
                }
                curdl = dl;
                A0 = A1 = A2 = A3 = A4 = A5 = 0.f;
                const float* xr = &xrw[dl * 5];
                xr0 = xr[0]; xr1 = xr[1]; xr2 = xr[2]; xr3 = xr[3]; xr4 = xr[4];
            }
            float t, lg = 0.f;
            t = xs.x + xr0; t = (t >= 0.f) ? t : 0.2f * t; lg += t * a0;
            t = xs.y + xr1; t = (t >= 0.f) ? t : 0.2f * t; lg += t * a1;
            t = xs.z + xr2; t = (t >= 0.f) ? t : 0.2f * t; lg += t * a2;
            t = xs.w + xr3; t = (t >= 0.f) ? t : 0.2f * t; lg += t * a3;
            t = xs4  + xr4; t = (t >= 0.f) ? t : 0.2f * t; lg += t * a4;
            const float w = __expf(lg);
            A0 += w * xs.x; A1 += w * xs.y; A2 += w * xs.z;
            A3 += w * xs.w; A4 += w * xs4;  A5 += w;
        }
        if (curdl >= 0) {
            atomicAdd(&acc[curdl][0], A0);
            atomicAdd(&acc[curdl][1], A1);
            atomicAdd(&acc[curdl][2], A2);
            atomicAdd(&acc[curdl][3], A3);
            atomicAdd(&acc[curdl][4], A4);
            atomicAdd(&acc[curdl][5], A5);
        }
        __syncthreads();
    } else if (seg > CAP) {
        // --- overflow fallback: direct per-edge atomics (never for random) ---
        for (int i = eb + tid; i < ee; i += 256) {
            const int v  = rs[i];
            const int s  = v >> BSH;
            const int dl = v & (NPB - 1);
            const size_t s8 = (size_t)s * 8;
            const float4 xs = *(const float4*)(xl8 + s8);
            const float  xs4 = xl8[s8 + 4];
            const float* xr = &xrw[dl * 5];
            float t, lg = 0.f;
            t = xs.x + xr[0]; t = (t >= 0.f) ? t : 0.2f * t; lg += t * a0;
            t = xs.y + xr[1]; t = (t >= 0.f) ? t : 0.2f * t; lg += t * a1;
            t = xs.z + xr[2]; t = (t >= 0.f) ? t : 0.2f * t; lg += t * a2;
            t = xs.w + xr[3]; t = (t >= 0.f) ? t : 0.2f * t; lg += t * a3;
            t = xs4  + xr[4]; t = (t >= 0.f) ? t : 0.2f * t; lg += t * a4;
            const float w = __expf(lg);
            atomicAdd(&acc[dl][0], w * xs.x);
            atomicAdd(&acc[dl][1], w * xs.y);
            atomicAdd(&acc[dl][2], w * xs.z);
            atomicAdd(&acc[dl][3], w * xs.w);
            atomicAdd(&acc[dl][4], w * xs4);
            atomicAdd(&acc[dl][5], w);
        }
        __syncthreads();
    } else {
        __syncthreads();
    }

    // --- epilogue: self-loop + divide + bias + LeakyReLU(0.1) ---
    const float b0 = bias[0], b1 = bias[1], b2 = bias[2], b3 = bias[3], b4 = bias[4];
    for (int l = tid; l < nn; l += 256) {
        const int node = node0 + l;
        const size_t s8 = (size_t)node * 8;
        const float4 xs = *(const float4*)(xl8 + s8);
        const float  xs4 = xl8[s8 + 4];
        const float* xr = &xrw[l * 5];

        float t, lg = 0.f;
        t = xs.x + xr[0]; t = (t >= 0.f) ? t : 0.2f * t; lg += t * a0;
        t = xs.y + xr[1]; t = (t >= 0.f) ? t : 0.2f * t; lg += t * a1;
        t = xs.z + xr[2]; t = (t >= 0.f) ? t : 0.2f * t; lg += t * a2;
        t = xs.w + xr[3]; t = (t >= 0.f) ? t : 0.2f * t; lg += t * a3;
        t = xs4  + xr[4]; t = (t >= 0.f) ? t : 0.2f * t; lg += t * a4;
        const float w = __expf(lg);

        const size_t d5 = (size_t)node * 5;
        const float inv = 1.0f / (acc[l][5] + w);
        float v;
        v = (acc[l][0] + w * xs.x) * inv + b0; xout[d5 + 0] = (v >= 0.f) ? v : 0.1f * v;
        v = (acc[l][1] + w * xs.y) * inv + b1; xout[d5 + 1] = (v >= 0.f) ? v : 0.1f * v;
        v = (acc[l][2] + w * xs.z) * inv + b2; xout[d5 + 2] = (v >= 0.f) ? v : 0.1f * v;
        v = (acc[l][3] + w * xs.w) * inv + b3; xout[d5 + 3] = (v >= 0.f) ? v : 0.1f * v;
        v = (acc[l][4] + w * xs4 ) * inv + b4; xout[d5 + 4] = (v >= 0.f) ? v : 0.1f * v;
    }
}

// ---------------------------------------------------------------------------
// k_mlp: fused projection + classifier.
// ---------------------------------------------------------------------------
__global__ __launch_bounds__(256) void k_mlp(
    const float* __restrict__ xp, const float* __restrict__ xs,
    const float* __restrict__ xv,
    const float* __restrict__ Wp1, const float* __restrict__ bp1,
    const float* __restrict__ Wp2, const float* __restrict__ bp2,
    const float* __restrict__ Wc1, const float* __restrict__ bc1,
    const float* __restrict__ Wc2, const float* __restrict__ bc2,
    float* __restrict__ out, int n)
{
    __shared__ float sW[257];
    const int tid = threadIdx.x;
    if (tid < 150) sW[tid] = Wp1[tid];
    if (tid < 10)  sW[150 + tid] = bp1[tid];
    if (tid < 50)  sW[160 + tid] = Wp2[tid];
    if (tid < 5)   sW[210 + tid] = bp2[tid];
    if (tid < 25)  sW[215 + tid] = Wc1[tid];
    if (tid < 5)   sW[240 + tid] = bc1[tid];
    if (tid < 10)  sW[245 + tid] = Wc2[tid];
    if (tid < 2)   sW[255 + tid] = bc2[tid];
    __syncthreads();

    const int node = blockIdx.x * 256 + tid;
    if (node >= n) return;
    const size_t n5 = (size_t)node * KOUT;

    float h[15];
#pragma unroll
    for (int k = 0; k < 5; ++k) {
        h[k]      = xp[n5 + k];
        h[5 + k]  = xs[n5 + k];
        h[10 + k] = xv[n5 + k];
    }

    float t1[10];
#pragma unroll
    for (int o = 0; o < 10; ++o) {
        float a = sW[150 + o];
#pragma unroll
        for (int i = 0; i < 15; ++i) a += h[i] * sW[i * 10 + o];
        t1[o] = (a >= 0.f) ? a : 0.1f * a;
    }

    float t2[5];
#pragma unroll
    for (int o = 0; o < 5; ++o) {
        float a = sW[210 + o];
#pragma unroll
        for (int i = 0; i < 10; ++i) a += t1[i] * sW[160 + i * 5 + o];
        t2[o] = a;
    }

    float t3[5];
#pragma unroll
    for (int o = 0; o < 5; ++o) {
        float a = sW[240 + o];
#pragma unroll
        for (int i = 0; i < 5; ++i) a += t2[i] * sW[215 + i * 5 + o];
        t3[o] = (a >= 0.f) ? a : 0.1f * a;
    }

    float o0 = sW[255], o1 = sW[256];
#pragma unroll
    for (int i = 0; i < 5; ++i) {
        o0 += t3[i] * sW[245 + i * 2 + 0];
        o1 += t3[i] * sW[245 + i * 2 + 1];
    }
    out[(size_t)node * 2 + 0] = o0;
    out[(size_t)node * 2 + 1] = o1;
}

// ---------------------------------------------------------------------------
extern "C" void kernel_launch(void* const* d_in, const int* in_sizes, int n_in,
                              void* d_out, int out_size, void* d_ws, size_t ws_size,
                              hipStream_t stream)
{
    const float* x = (const float*)d_in[0];
    const int n = in_sizes[0] / KIN;          // 1,000,000
    const int E = in_sizes[1] / 2;            // 8,000,000
    const int NB = (n + NPB - 1) >> BSH;      // 1954 buckets (needs n <= 2^20)

    const int* ei[3] = { (const int*)d_in[1], (const int*)d_in[2], (const int*)d_in[3] };
    const float *Wl[3], *Wr[3], *att[3], *bias[3];
    for (int r = 0; r < 3; ++r) {
        const int base = 4 + r * 4;
        Wl[r]   = (const float*)d_in[base + 0];
        Wr[r]   = (const float*)d_in[base + 1];
        att[r]  = (const float*)d_in[base + 2];
        bias[r] = (const float*)d_in[base + 3];
    }
    const float* Wp1 = (const float*)d_in[16];
    const float* bp1 = (const float*)d_in[17];
    const float* Wp2 = (const float*)d_in[18];
    const float* bp2 = (const float*)d_in[19];
    const float* Wc1 = (const float*)d_in[20];
    const float* bc1 = (const float*)d_in[21];
    const float* Wc2 = (const float*)d_in[22];
    const float* bc2 = (const float*)d_in[23];

    // Fused layout A (~313MB): xout[15n] | xl8[3][8n] | xr5[3][5n] |
    //   rs3[3E] | totals3[3*NBH] | base3[3*BROW]
    // Fallback layout B (~144MB): xout[15n] | xl8[8n] | xr5[5n] |
    //   rs[E] | totals[NBH] | base[BROW]
    // hist3 overlays xout[10n..15n) (dead until last gather writes it).
    const size_t intsA = (size_t)3 * E + 3 * NBH + 3 * BROW;
    const size_t need_A = ((size_t)54 * n + intsA) * 4;
    const bool fused = ws_size >= need_A;

    float* ws   = (float*)d_ws;
    float* xout = ws;
    float* xl8  = ws + (size_t)15 * n;
    float* xr5  = xl8 + (fused ? (size_t)24 * n : (size_t)8 * n);
    int*   rs3  = (int*)(xr5 + (fused ? (size_t)15 * n : (size_t)5 * n));
    int*   totals3 = rs3 + (fused ? (size_t)3 * E : (size_t)E);
    int*   base3   = totals3 + (fused ? 3 * NBH : NBH);
    int*   hist3   = (int*)(xout + (size_t)10 * n);   // overlay on xv slice

    const int nb_node = (n + 255) / 256;
    const int nb_cols = (NB + 255) / 256;

    if (fused) {
        k_node3<<<nb_node, 256, 0, stream>>>(x, Wl[0], Wr[0], Wl[1], Wr[1],
                                             Wl[2], Wr[2], xl8, xr5, n);
        k_hist3   <<<dim3(NBLK, 3),    BTH,  0, stream>>>(ei[0] + E, ei[1] + E,
                                                          ei[2] + E, E, NB, hist3);
        k_sumoffs3<<<dim3(nb_cols, 3), 256,  0, stream>>>(hist3, NB, totals3);
        k_scan3   <<<3,                1024, 0, stream>>>(totals3, E, NB, base3);
        k_scatter3<<<dim3(NBLK, 3),    BTH,  0, stream>>>(
            ei[0], ei[1], ei[2], ei[0] + E, ei[1] + E, ei[2] + E,
            E, NB, hist3, base3, rs3);
        k_gather4<3><<<3 * NB, 256, 0, stream>>>(
            rs3, base3, xl8, xr5,
            att[0], att[1], att[2], bias[0], bias[1], bias[2],
            xout, n, E);
    } else {
        for (int r = 0; r < 3; ++r) {
            float* xo = xout + (size_t)r * 5 * n;
            k_node1<<<nb_node, 256, 0, stream>>>(x, Wl[r], Wr[r], xl8, xr5, n);
            k_hist3   <<<dim3(NBLK, 1),    BTH,  0, stream>>>(ei[r] + E, ei[r] + E,
                                                              ei[r] + E, E, NB, hist3);
            k_sumoffs3<<<dim3(nb_cols, 1), 256,  0, stream>>>(hist3, NB, totals3);
            k_scan3   <<<1,                1024, 0, stream>>>(totals3, E, NB, base3);
            k_scatter3<<<dim3(NBLK, 1),    BTH,  0, stream>>>(
                ei[r], ei[r], ei[r], ei[r] + E, ei[r] + E, ei[r] + E,
                E, NB, hist3, base3, rs3);
            k_gather4<1><<<NB, 256, 0, stream>>>(
                rs3, base3, xl8, xr5,
                att[r], att[r], att[r], bias[r], bias[r], bias[r],
                xo, n, E);
        }
    }

    k_mlp<<<nb_node, 256, 0, stream>>>(xout, xout + (size_t)5 * n, xout + (size_t)10 * n,
                                       Wp1, bp1, Wp2, bp2, Wc1, bc1, Wc2, bc2,
                                       (float*)d_out, n);
}

// Round 11
// 1065.536 us; speedup vs baseline: 2.8195x; 1.0477x over previous
//
#include <hip/hip_runtime.h>

static constexpr int KIN  = 25;
static constexpr int KOUT = 5;
static constexpr int NBLK = 512;      // blocks for hist/scatter
static constexpr int BTH  = 1024;     // threads for hist/scatter
static constexpr int BSH  = 9;        // log2 nodes per bucket
static constexpr int NPB  = 1 << BSH; // 512 nodes per bucket
static constexpr int NBH  = 2048;     // hist row stride / max buckets
static constexpr int BROW = NBH + 1;  // base row stride (incl. sentinel)
static constexpr int CAP  = 5120;     // max edges per bucket for LDS sort (16 sigma)

// ---------------------------------------------------------------------------
// k_node1: single-relation transforms (fallback layout).
// ---------------------------------------------------------------------------
__global__ __launch_bounds__(256) void k_node1(
    const float* __restrict__ x,
    const float* __restrict__ Wl, const float* __restrict__ Wr,
    float* __restrict__ xl8, float* __restrict__ xr5, int n)
{
    __shared__ float sWl[KIN * KOUT];
    __shared__ float sWr[KIN * KOUT];
    __shared__ float sx[256 * KIN];

    const int tid = threadIdx.x;
    if (tid < KIN * KOUT) { sWl[tid] = Wl[tid]; sWr[tid] = Wr[tid]; }

    const int base = blockIdx.x * 256;
    const int cnt  = min(256, n - base);
    const size_t xbase = (size_t)base * KIN;
    for (int i = tid; i < cnt * KIN; i += 256) sx[i] = x[xbase + i];
    __syncthreads();

    if (tid >= cnt) return;
    const int node = base + tid;

    float xls[KOUT] = {0.f, 0.f, 0.f, 0.f, 0.f};
    float xrs[KOUT] = {0.f, 0.f, 0.f, 0.f, 0.f};
    const float* xp = &sx[tid * KIN];
#pragma unroll
    for (int i = 0; i < KIN; ++i) {
        const float xv = xp[i];
#pragma unroll
        for (int o = 0; o < KOUT; ++o) {
            xls[o] += xv * sWl[i * KOUT + o];
            xrs[o] += xv * sWr[i * KOUT + o];
        }
    }

    const size_t n8 = (size_t)node * 8;
    float4 v4;
    v4.x = xls[0]; v4.y = xls[1]; v4.z = xls[2]; v4.w = xls[3];
    *(float4*)(xl8 + n8) = v4;
    xl8[n8 + 4] = xls[4];
    const size_t n5 = (size_t)node * 5;
#pragma unroll
    for (int o = 0; o < KOUT; ++o) xr5[n5 + o] = xrs[o];
}

// ---------------------------------------------------------------------------
// k_histnode: fused dispatch. Blocks x<NBLK: dst-bucket histogram (rel = y,
// int4 edge reads). Blocks x>=NBLK (y==0 only): node transforms for all 3
// relations (independent work overlapped with the histogram).
// ---------------------------------------------------------------------------
__global__ __launch_bounds__(BTH) void k_histnode(
    const int* __restrict__ d0p, const int* __restrict__ d1p,
    const int* __restrict__ d2p, int E, int NB, int* __restrict__ hist3,
    const float* __restrict__ x,
    const float* __restrict__ Wl0, const float* __restrict__ Wr0,
    const float* __restrict__ Wl1, const float* __restrict__ Wr1,
    const float* __restrict__ Wl2, const float* __restrict__ Wr2,
    float* __restrict__ xl8, float* __restrict__ xr5, int n, int NNB)
{
    __shared__ float smem[7424];          // 29 KB (union: hist | weights+sx)
    const int y = blockIdx.y, bx = blockIdx.x, tid = threadIdx.x;

    if (bx < NBLK) {
        // ---- histogram for relation y ----
        int* h = (int*)smem;
        const int* dst = (y == 0) ? d0p : (y == 1 ? d1p : d2p);
        int* hist_blk = hist3 + (size_t)y * NBLK * NBH;
        for (int i = tid; i < NB; i += BTH) h[i] = 0;
        __syncthreads();
        const int chunk = (((E + NBLK - 1) / NBLK) + 3) & ~3;
        const int eb = bx * chunk, ee = min(E, eb + chunk);
        const int vend = eb + ((ee - eb) & ~3);
        for (int i = eb + tid * 4; i < vend; i += BTH * 4) {
            const int4 d4 = *(const int4*)(dst + i);
            atomicAdd(&h[d4.x >> BSH], 1);
            atomicAdd(&h[d4.y >> BSH], 1);
            atomicAdd(&h[d4.z >> BSH], 1);
            atomicAdd(&h[d4.w >> BSH], 1);
        }
        for (int i = vend + tid; i < ee; i += BTH)
            atomicAdd(&h[dst[i] >> BSH], 1);
        __syncthreads();
        for (int i = tid; i < NB; i += BTH) hist_blk[bx * NBH + i] = h[i];
        return;
    }

    // ---- node transforms (y == 0 row only) ----
    if (y != 0) return;
    const int g = bx - NBLK;
    if (g >= NNB) return;

    float* sW = smem;                     // 6 x 125
    float* sx = smem + 768;               // 256 x 25
    if (tid < KIN * KOUT) {
        sW[tid]       = Wl0[tid]; sW[125 + tid] = Wr0[tid];
        sW[250 + tid] = Wl1[tid]; sW[375 + tid] = Wr1[tid];
        sW[500 + tid] = Wl2[tid]; sW[625 + tid] = Wr2[tid];
    }

    for (int sub = 0; sub < 4; ++sub) {
        const int base = g * 1024 + sub * 256;
        if (base >= n) break;
        const int cnt = min(256, n - base);
        __syncthreads();
        const size_t xb = (size_t)base * KIN;
        for (int i = tid; i < cnt * KIN; i += BTH) sx[i] = x[xb + i];
        __syncthreads();
        if (tid < cnt) {
            const int node = base + tid;
            float xls[3][KOUT] = {};
            float xrs[3][KOUT] = {};
            const float* xp = &sx[tid * KIN];
#pragma unroll
            for (int i = 0; i < KIN; ++i) {
                const float xv = xp[i];
#pragma unroll
                for (int r = 0; r < 3; ++r)
#pragma unroll
                    for (int o = 0; o < KOUT; ++o) {
                        xls[r][o] += xv * sW[r * 250 + i * KOUT + o];
                        xrs[r][o] += xv * sW[r * 250 + 125 + i * KOUT + o];
                    }
            }
#pragma unroll
            for (int r = 0; r < 3; ++r) {
                const size_t n8 = (size_t)r * n * 8 + (size_t)node * 8;
                float4 v4;
                v4.x = xls[r][0]; v4.y = xls[r][1];
                v4.z = xls[r][2]; v4.w = xls[r][3];
                *(float4*)(xl8 + n8) = v4;
                xl8[n8 + 4] = xls[r][4];
                const size_t n5 = (size_t)r * n * 5 + (size_t)node * 5;
#pragma unroll
                for (int o = 0; o < KOUT; ++o) xr5[n5 + o] = xrs[r][o];
            }
        }
    }
}

// ---------------------------------------------------------------------------
// k_sumoffs3: per bucket, hist rows -> exclusive per-block offsets + totals.
// ---------------------------------------------------------------------------
__global__ __launch_bounds__(256) void k_sumoffs3(
    int* __restrict__ hist3, int NB, int* __restrict__ totals3)
{
    const int rel = blockIdx.y;
    int* hist_blk = hist3 + (size_t)rel * NBLK * NBH;
    int* totals   = totals3 + rel * NBH;
    const int i = blockIdx.x * 256 + threadIdx.x;
    if (i >= NB) return;
    int s = 0;
    for (int b = 0; b < NBLK; ++b) {
        const int t = hist_blk[b * NBH + i];
        hist_blk[b * NBH + i] = s;
        s += t;
    }
    totals[i] = s;
}

// ---------------------------------------------------------------------------
// k_scan3: exclusive scan of totals -> base per relation. blockIdx.x = rel.
// ---------------------------------------------------------------------------
__global__ __launch_bounds__(1024) void k_scan3(
    const int* __restrict__ totals3, int E, int NB, int* __restrict__ base3)
{
    __shared__ int s[1024];
    const int rel = blockIdx.x;
    const int* totals = totals3 + rel * NBH;
    int* base = base3 + rel * BROW;

    const int t = threadIdx.x;
    const int i0 = 2 * t, i1 = 2 * t + 1;
    const int t0 = (i0 < NB) ? totals[i0] : 0;
    const int t1 = (i1 < NB) ? totals[i1] : 0;
    const int pair = t0 + t1;
    s[t] = pair;
    __syncthreads();
    for (int off = 1; off < 1024; off <<= 1) {
        int v = (t >= off) ? s[t - off] : 0;
        __syncthreads();
        s[t] += v;
        __syncthreads();
    }
    const int excl = s[t] - pair;
    base[i0] = excl;
    base[i1] = excl + t0;
    if (t == 1023) base[NBH] = E;
}

// ---------------------------------------------------------------------------
// k_scatter3: single pass, no global atomics, int4 edge reads.
// ---------------------------------------------------------------------------
__global__ __launch_bounds__(BTH) void k_scatter3(
    const int* __restrict__ s0p, const int* __restrict__ s1p,
    const int* __restrict__ s2p,
    const int* __restrict__ d0p, const int* __restrict__ d1p,
    const int* __restrict__ d2p,
    int E, int NB,
    const int* __restrict__ hist3, const int* __restrict__ base3,
    int* __restrict__ rs3)
{
    __shared__ int cur[NBH];
    const int rel = blockIdx.y, b = blockIdx.x, tid = threadIdx.x;
    const int* src = (rel == 0) ? s0p : (rel == 1 ? s1p : s2p);
    const int* dst = (rel == 0) ? d0p : (rel == 1 ? d1p : d2p);
    const int* hist_blk = hist3 + (size_t)rel * NBLK * NBH;
    const int* base = base3 + rel * BROW;
    int* rs = rs3 + (size_t)rel * E;

    for (int i = tid; i < NB; i += BTH)
        cur[i] = base[i] + hist_blk[b * NBH + i];
    __syncthreads();
    const int chunk = (((E + NBLK - 1) / NBLK) + 3) & ~3;
    const int eb = b * chunk, ee = min(E, eb + chunk);
    const int vend = eb + ((ee - eb) & ~3);
    for (int i = eb + tid * 4; i < vend; i += BTH * 4) {
        const int4 s4 = *(const int4*)(src + i);
        const int4 d4 = *(const int4*)(dst + i);
        int p;
        p = atomicAdd(&cur[d4.x >> BSH], 1); rs[p] = (s4.x << BSH) | (d4.x & (NPB - 1));
        p = atomicAdd(&cur[d4.y >> BSH], 1); rs[p] = (s4.y << BSH) | (d4.y & (NPB - 1));
        p = atomicAdd(&cur[d4.z >> BSH], 1); rs[p] = (s4.z << BSH) | (d4.z & (NPB - 1));
        p = atomicAdd(&cur[d4.w >> BSH], 1); rs[p] = (s4.w << BSH) | (d4.w & (NPB - 1));
    }
    for (int i = vend + tid; i < ee; i += BTH) {
        const int d = dst[i];
        const int pos = atomicAdd(&cur[d >> BSH], 1);
        rs[pos] = (src[i] << BSH) | (d & (NPB - 1));
    }
}

// ---------------------------------------------------------------------------
// k_gather4: one block per (relation, bucket), REL-MAJOR block order so one
// relation's 32MB xl8 is hot at a time. In-LDS counting sort by dst-local,
// then chunked register accumulation. Epilogue folds self-loop+bias+lrelu.
// ---------------------------------------------------------------------------
template <int NREL>
__global__ __launch_bounds__(256) void k_gather4(
    const int* __restrict__ rs3, const int* __restrict__ base3,
    const float* __restrict__ xl8a, const float* __restrict__ xr5a,
    const float* __restrict__ at0, const float* __restrict__ at1,
    const float* __restrict__ at2,
    const float* __restrict__ bi0, const float* __restrict__ bi1,
    const float* __restrict__ bi2,
    float* __restrict__ xouta, int n, int E, int NB)
{
    __shared__ float acc[NPB][6];       // 12 KB
    __shared__ float xrw[NPB * 5];      // 10 KB
    __shared__ int   cur[NPB];          // 2 KB
    __shared__ int   sorted[CAP];       // 20 KB
    __shared__ int   sc[256];           // 1 KB

    const int bx  = blockIdx.x;
    const int rel = (NREL == 1) ? 0 : bx / NB;     // rel-major
    const int bkt = (NREL == 1) ? bx : bx % NB;

    const int*   rs   = rs3 + (size_t)rel * E;
    const int*   base = base3 + rel * BROW;
    const float* xl8  = xl8a + (size_t)rel * 8 * n;
    const float* xr5  = xr5a + (size_t)rel * 5 * n;
    const float* att  = (rel == 0) ? at0 : (rel == 1 ? at1 : at2);
    const float* bias = (rel == 0) ? bi0 : (rel == 1 ? bi1 : bi2);
    float*       xout = xouta + (size_t)rel * 5 * n;

    const int tid = threadIdx.x;
    const int node0 = bkt << BSH;
    const int nn = min(NPB, n - node0);

    for (int i = tid; i < NPB * 6; i += 256) ((float*)acc)[i] = 0.f;
    for (int i = tid; i < nn * 5; i += 256) xrw[i] = xr5[(size_t)node0 * 5 + i];
    for (int i = tid; i < NPB; i += 256) cur[i] = 0;
    __syncthreads();

    const float a0 = att[0], a1 = att[1], a2 = att[2], a3 = att[3], a4 = att[4];
    const int eb = base[bkt], ee = base[bkt + 1];
    const int seg = ee - eb;

    if (seg > 0 && seg <= CAP) {
        for (int i = eb + tid; i < ee; i += 256)
            atomicAdd(&cur[rs[i] & (NPB - 1)], 1);
        __syncthreads();
        const int h0 = cur[2 * tid], h1 = cur[2 * tid + 1];
        const int pair = h0 + h1;
        sc[tid] = pair;
        __syncthreads();
        for (int off = 1; off < 256; off <<= 1) {
            const int v = (tid >= off) ? sc[tid - off] : 0;
            __syncthreads();
            sc[tid] += v;
            __syncthreads();
        }
        const int excl = sc[tid] - pair;
        cur[2 * tid] = excl;
        cur[2 * tid + 1] = excl + h0;
        __syncthreads();
        for (int i = eb + tid; i < ee; i += 256) {
            const int v = rs[i];
            const int p = atomicAdd(&cur[v & (NPB - 1)], 1);
            sorted[p] = v;
        }
        __syncthreads();
        const int C  = (seg + 255) / 256;
        const int s0 = tid * C;
        const int s1 = min(seg, s0 + C);
        int curdl = -1;
        float A0 = 0.f, A1 = 0.f, A2 = 0.f, A3 = 0.f, A4 = 0.f, A5 = 0.f;
        float xr0 = 0.f, xr1 = 0.f, xr2 = 0.f, xr3 = 0.f, xr4 = 0.f;
        for (int i = s0; i < s1; ++i) {
            const int v  = sorted[i];
            const int dl = v & (NPB - 1);
            const int s  = v >> BSH;
            const size_t s8 = (size_t)s * 8;
            const float4 xs = *(const float4*)(xl8 + s8);
            const float  xs4 = xl8[s8 + 4];
            if (dl != curdl) {
                if (curdl >= 0) {
                    atomicAdd(&acc[curdl][0], A0);
                    atomicAdd(&acc[curdl][1], A1);
                    atomicAdd(&acc[curdl][2], A2);
                    atomicAdd(&acc[curdl][3], A3);
                    atomicAdd(&acc[curdl][4], A4);
                    atomicAdd(&acc[curdl][5], A5);
                }
                curdl = dl;
                A0 = A1 = A2 = A3 = A4 = A5 = 0.f;
                const float* xr = &xrw[dl * 5];
                xr0 = xr[0]; xr1 = xr[1]; xr2 = xr[2]; xr3 = xr[3]; xr4 = xr[4];
            }
            float t, lg = 0.f;
            t = xs.x + xr0; t = (t >= 0.f) ? t : 0.2f * t; lg += t * a0;
            t = xs.y + xr1; t = (t >= 0.f) ? t : 0.2f * t; lg += t * a1;
            t = xs.z + xr2; t = (t >= 0.f) ? t : 0.2f * t; lg += t * a2;
            t = xs.w + xr3; t = (t >= 0.f) ? t : 0.2f * t; lg += t * a3;
            t = xs4  + xr4; t = (t >= 0.f) ? t : 0.2f * t; lg += t * a4;
            const float w = __expf(lg);
            A0 += w * xs.x; A1 += w * xs.y; A2 += w * xs.z;
            A3 += w * xs.w; A4 += w * xs4;  A5 += w;
        }
        if (curdl >= 0) {
            atomicAdd(&acc[curdl][0], A0);
            atomicAdd(&acc[curdl][1], A1);
            atomicAdd(&acc[curdl][2], A2);
            atomicAdd(&acc[curdl][3], A3);
            atomicAdd(&acc[curdl][4], A4);
            atomicAdd(&acc[curdl][5], A5);
        }
        __syncthreads();
    } else if (seg > CAP) {
        for (int i = eb + tid; i < ee; i += 256) {
            const int v  = rs[i];
            const int s  = v >> BSH;
            const int dl = v & (NPB - 1);
            const size_t s8 = (size_t)s * 8;
            const float4 xs = *(const float4*)(xl8 + s8);
            const float  xs4 = xl8[s8 + 4];
            const float* xr = &xrw[dl * 5];
            float t, lg = 0.f;
            t = xs.x + xr[0]; t = (t >= 0.f) ? t : 0.2f * t; lg += t * a0;
            t = xs.y + xr[1]; t = (t >= 0.f) ? t : 0.2f * t; lg += t * a1;
            t = xs.z + xr[2]; t = (t >= 0.f) ? t : 0.2f * t; lg += t * a2;
            t = xs.w + xr[3]; t = (t >= 0.f) ? t : 0.2f * t; lg += t * a3;
            t = xs4  + xr[4]; t = (t >= 0.f) ? t : 0.2f * t; lg += t * a4;
            const float w = __expf(lg);
            atomicAdd(&acc[dl][0], w * xs.x);
            atomicAdd(&acc[dl][1], w * xs.y);
            atomicAdd(&acc[dl][2], w * xs.z);
            atomicAdd(&acc[dl][3], w * xs.w);
            atomicAdd(&acc[dl][4], w * xs4);
            atomicAdd(&acc[dl][5], w);
        }
        __syncthreads();
    } else {
        __syncthreads();
    }

    const float b0 = bias[0], b1 = bias[1], b2 = bias[2], b3 = bias[3], b4 = bias[4];
    for (int l = tid; l < nn; l += 256) {
        const int node = node0 + l;
        const size_t s8 = (size_t)node * 8;
        const float4 xs = *(const float4*)(xl8 + s8);
        const float  xs4 = xl8[s8 + 4];
        const float* xr = &xrw[l * 5];

        float t, lg = 0.f;
        t = xs.x + xr[0]; t = (t >= 0.f) ? t : 0.2f * t; lg += t * a0;
        t = xs.y + xr[1]; t = (t >= 0.f) ? t : 0.2f * t; lg += t * a1;
        t = xs.z + xr[2]; t = (t >= 0.f) ? t : 0.2f * t; lg += t * a2;
        t = xs.w + xr[3]; t = (t >= 0.f) ? t : 0.2f * t; lg += t * a3;
        t = xs4  + xr[4]; t = (t >= 0.f) ? t : 0.2f * t; lg += t * a4;
        const float w = __expf(lg);

        const size_t d5 = (size_t)node * 5;
        const float inv = 1.0f / (acc[l][5] + w);
        float v;
        v = (acc[l][0] + w * xs.x) * inv + b0; xout[d5 + 0] = (v >= 0.f) ? v : 0.1f * v;
        v = (acc[l][1] + w * xs.y) * inv + b1; xout[d5 + 1] = (v >= 0.f) ? v : 0.1f * v;
        v = (acc[l][2] + w * xs.z) * inv + b2; xout[d5 + 2] = (v >= 0.f) ? v : 0.1f * v;
        v = (acc[l][3] + w * xs.w) * inv + b3; xout[d5 + 3] = (v >= 0.f) ? v : 0.1f * v;
        v = (acc[l][4] + w * xs4 ) * inv + b4; xout[d5 + 4] = (v >= 0.f) ? v : 0.1f * v;
    }
}

// ---------------------------------------------------------------------------
// k_mlp: fused projection + classifier.
// ---------------------------------------------------------------------------
__global__ __launch_bounds__(256) void k_mlp(
    const float* __restrict__ xp, const float* __restrict__ xs,
    const float* __restrict__ xv,
    const float* __restrict__ Wp1, const float* __restrict__ bp1,
    const float* __restrict__ Wp2, const float* __restrict__ bp2,
    const float* __restrict__ Wc1, const float* __restrict__ bc1,
    const float* __restrict__ Wc2, const float* __restrict__ bc2,
    float* __restrict__ out, int n)
{
    __shared__ float sW[257];
    const int tid = threadIdx.x;
    if (tid < 150) sW[tid] = Wp1[tid];
    if (tid < 10)  sW[150 + tid] = bp1[tid];
    if (tid < 50)  sW[160 + tid] = Wp2[tid];
    if (tid < 5)   sW[210 + tid] = bp2[tid];
    if (tid < 25)  sW[215 + tid] = Wc1[tid];
    if (tid < 5)   sW[240 + tid] = bc1[tid];
    if (tid < 10)  sW[245 + tid] = Wc2[tid];
    if (tid < 2)   sW[255 + tid] = bc2[tid];
    __syncthreads();

    const int node = blockIdx.x * 256 + tid;
    if (node >= n) return;
    const size_t n5 = (size_t)node * KOUT;

    float h[15];
#pragma unroll
    for (int k = 0; k < 5; ++k) {
        h[k]      = xp[n5 + k];
        h[5 + k]  = xs[n5 + k];
        h[10 + k] = xv[n5 + k];
    }

    float t1[10];
#pragma unroll
    for (int o = 0; o < 10; ++o) {
        float a = sW[150 + o];
#pragma unroll
        for (int i = 0; i < 15; ++i) a += h[i] * sW[i * 10 + o];
        t1[o] = (a >= 0.f) ? a : 0.1f * a;
    }

    float t2[5];
#pragma unroll
    for (int o = 0; o < 5; ++o) {
        float a = sW[210 + o];
#pragma unroll
        for (int i = 0; i < 10; ++i) a += t1[i] * sW[160 + i * 5 + o];
        t2[o] = a;
    }

    float t3[5];
#pragma unroll
    for (int o = 0; o < 5; ++o) {
        float a = sW[240 + o];
#pragma unroll
        for (int i = 0; i < 5; ++i) a += t2[i] * sW[215 + i * 5 + o];
        t3[o] = (a >= 0.f) ? a : 0.1f * a;
    }

    float o0 = sW[255], o1 = sW[256];
#pragma unroll
    for (int i = 0; i < 5; ++i) {
        o0 += t3[i] * sW[245 + i * 2 + 0];
        o1 += t3[i] * sW[245 + i * 2 + 1];
    }
    out[(size_t)node * 2 + 0] = o0;
    out[(size_t)node * 2 + 1] = o1;
}

// ---------------------------------------------------------------------------
extern "C" void kernel_launch(void* const* d_in, const int* in_sizes, int n_in,
                              void* d_out, int out_size, void* d_ws, size_t ws_size,
                              hipStream_t stream)
{
    const float* x = (const float*)d_in[0];
    const int n = in_sizes[0] / KIN;          // 1,000,000
    const int E = in_sizes[1] / 2;            // 8,000,000
    const int NB = (n + NPB - 1) >> BSH;      // 1954 buckets (needs n <= 2^20)

    const int* ei[3] = { (const int*)d_in[1], (const int*)d_in[2], (const int*)d_in[3] };
    const float *Wl[3], *Wr[3], *att[3], *bias[3];
    for (int r = 0; r < 3; ++r) {
        const int base = 4 + r * 4;
        Wl[r]   = (const float*)d_in[base + 0];
        Wr[r]   = (const float*)d_in[base + 1];
        att[r]  = (const float*)d_in[base + 2];
        bias[r] = (const float*)d_in[base + 3];
    }
    const float* Wp1 = (const float*)d_in[16];
    const float* bp1 = (const float*)d_in[17];
    const float* Wp2 = (const float*)d_in[18];
    const float* bp2 = (const float*)d_in[19];
    const float* Wc1 = (const float*)d_in[20];
    const float* bc1 = (const float*)d_in[21];
    const float* Wc2 = (const float*)d_in[22];
    const float* bc2 = (const float*)d_in[23];

    // Fused layout A (~313MB): xout[15n] | xl8[3][8n] | xr5[3][5n] |
    //   rs3[3E] | totals3[3*NBH] | base3[3*BROW]
    // Fallback layout B (~144MB): xout[15n] | xl8[8n] | xr5[5n] |
    //   rs[E] | totals[NBH] | base[BROW]
    // hist3 overlays xout[10n..15n) (dead until last gather writes it).
    const size_t intsA = (size_t)3 * E + 3 * NBH + 3 * BROW;
    const size_t need_A = ((size_t)54 * n + intsA) * 4;
    const bool fused = ws_size >= need_A;

    float* ws   = (float*)d_ws;
    float* xout = ws;
    float* xl8  = ws + (size_t)15 * n;
    float* xr5  = xl8 + (fused ? (size_t)24 * n : (size_t)8 * n);
    int*   rs3  = (int*)(xr5 + (fused ? (size_t)15 * n : (size_t)5 * n));
    int*   totals3 = rs3 + (fused ? (size_t)3 * E : (size_t)E);
    int*   base3   = totals3 + (fused ? 3 * NBH : NBH);
    int*   hist3   = (int*)(xout + (size_t)10 * n);   // overlay on xv slice

    const int nb_node = (n + 255) / 256;
    const int nb_cols = (NB + 255) / 256;
    const int NNB     = (n + 1023) / 1024;            // node groups (1024/blk)

    if (fused) {
        k_histnode<<<dim3(NBLK + NNB, 3), BTH, 0, stream>>>(
            ei[0] + E, ei[1] + E, ei[2] + E, E, NB, hist3,
            x, Wl[0], Wr[0], Wl[1], Wr[1], Wl[2], Wr[2], xl8, xr5, n, NNB);
        k_sumoffs3<<<dim3(nb_cols, 3), 256,  0, stream>>>(hist3, NB, totals3);
        k_scan3   <<<3,                1024, 0, stream>>>(totals3, E, NB, base3);
        k_scatter3<<<dim3(NBLK, 3),    BTH,  0, stream>>>(
            ei[0], ei[1], ei[2], ei[0] + E, ei[1] + E, ei[2] + E,
            E, NB, hist3, base3, rs3);
        k_gather4<3><<<3 * NB, 256, 0, stream>>>(
            rs3, base3, xl8, xr5,
            att[0], att[1], att[2], bias[0], bias[1], bias[2],
            xout, n, E, NB);
    } else {
        for (int r = 0; r < 3; ++r) {
            float* xo = xout + (size_t)r * 5 * n;
            k_node1<<<nb_node, 256, 0, stream>>>(x, Wl[r], Wr[r], xl8, xr5, n);
            k_histnode<<<dim3(NBLK, 1), BTH, 0, stream>>>(
                ei[r] + E, ei[r] + E, ei[r] + E, E, NB, hist3,
                x, Wl[r], Wr[r], Wl[r], Wr[r], Wl[r], Wr[r], xl8, xr5, n, 0);
            k_sumoffs3<<<dim3(nb_cols, 1), 256,  0, stream>>>(hist3, NB, totals3);
            k_scan3   <<<1,                1024, 0, stream>>>(totals3, E, NB, base3);
            k_scatter3<<<dim3(NBLK, 1),    BTH,  0, stream>>>(
                ei[r], ei[r], ei[r], ei[r] + E, ei[r] + E, ei[r] + E,
                E, NB, hist3, base3, rs3);
            k_gather4<1><<<NB, 256, 0, stream>>>(
                rs3, base3, xl8, xr5,
                att[r], att[r], att[r], bias[r], bias[r], bias[r],
                xo, n, E, NB);
        }
    }

    k_mlp<<<nb_node, 256, 0, stream>>>(xout, xout + (size_t)5 * n, xout + (size_t)10 * n,
                                       Wp1, bp1, Wp2, bp2, Wc1, bc1, Wc2, bc2,
                                       (float*)d_out, n);
}